// Round 2
// baseline (329.001 us; speedup 1.0000x reference)
//
#include <hip/hip_runtime.h>
#include <hip/hip_fp16.h>
#include <hip/hip_cooperative_groups.h>

namespace cg = cooperative_groups;

typedef _Float16 f16;
typedef f16 f16x4 __attribute__((ext_vector_type(4)));
typedef f16 f16x8 __attribute__((ext_vector_type(8)));
typedef float f32x4 __attribute__((ext_vector_type(4)));

#define NTOK 32768   // B*S
#define KDIM 512
#define SLEN 4096
#define BATCH 8
#define WSZ  262144  // 512*512

#define GLOAD_LDS16(g, l) __builtin_amdgcn_global_load_lds(                 \
    (const __attribute__((address_space(1))) void*)(g),                     \
    (__attribute__((address_space(3))) void*)(l), 16, 0, 0)

__device__ __forceinline__ float fast_tanh(float x) {
    float ax = fabsf(x);
    float t = __expf(-2.0f * ax);
    float r = (1.0f - t) / (1.0f + t);
    return copysignf(r, x);
}

// fp32 -> f16, 8 elements per call (chunk t covers [t*8, t*8+8))
__device__ __forceinline__ void cvt2048(const float* __restrict__ src, f16* __restrict__ dst, int t)
{
    const float4 v0 = *(const float4*)&src[(size_t)t * 8];
    const float4 v1 = *(const float4*)&src[(size_t)t * 8 + 4];
    f16x8 h;
    h[0]=(f16)v0.x; h[1]=(f16)v0.y; h[2]=(f16)v0.z; h[3]=(f16)v0.w;
    h[4]=(f16)v1.x; h[5]=(f16)v1.y; h[6]=(f16)v1.z; h[7]=(f16)v1.w;
    *(f16x8*)&dst[(size_t)t * 8] = h;
}

// 64x64 transpose tile, 512 threads, fp32 in -> f16 out (out = in^T)
__device__ __forceinline__ void tcvt64_512(const float* __restrict__ in, f16* __restrict__ out,
                                           int tile, int tid, float (*t)[65])
{
    const int c0 = (tile & 7) * 64, r0 = (tile >> 3) * 64;
    const int tr = tid >> 4;            // 0..31
    const int tc = (tid & 15) * 4;
    #pragma unroll
    for (int i = 0; i < 2; ++i) {
        const int row = tr + 32 * i;
        const float4 v = *(const float4*)&in[(size_t)(r0 + row) * 512 + c0 + tc];
        t[row][tc + 0] = v.x; t[row][tc + 1] = v.y;
        t[row][tc + 2] = v.z; t[row][tc + 3] = v.w;
    }
    __syncthreads();
    #pragma unroll
    for (int i = 0; i < 2; ++i) {
        const int cl = tr + 32 * i;
        f16x4 h;
        h[0] = (f16)t[tc + 0][cl]; h[1] = (f16)t[tc + 1][cl];
        h[2] = (f16)t[tc + 2][cl]; h[3] = (f16)t[tc + 3][cl];
        *(f16x4*)&out[(size_t)(c0 + cl) * 512 + r0 + tc] = h;
    }
}

// ============================================================================
// ONE cooperative kernel: stage P (prep) -> grid sync -> stage F (folds on 32
// blocks) -> grid sync -> stage C (fused 4-phase chain, verbatim round-1 code).
// 256 blocks x 512 threads, 1 block/CU (128 KB LDS forces it).
// ============================================================================
__global__ __launch_bounds__(512, 2)
void mega_kernel(const float* __restrict__ xs,
                 const float* __restrict__ W_xh0, const float* __restrict__ b_xh0,
                 const float* __restrict__ b_hh0, const float* __restrict__ W_hy0,
                 const float* __restrict__ b_hy0, const float* __restrict__ W_xh_h,
                 const float* __restrict__ b_xh_h, const float* __restrict__ W_hh_h,
                 const float* __restrict__ b_hh_h, const float* __restrict__ W_hy_h,
                 const float* __restrict__ b_hy_h,
                 float* __restrict__ out,
                 f16* __restrict__ Wp, f16* __restrict__ w_xhh,
                 f16* __restrict__ wt, float* __restrict__ bias)
{
    __shared__ __align__(16) char smem[131072];   // union: hbuf / tcvt / fold tiles

    const int tid  = threadIdx.x;
    const int bid  = blockIdx.x;
    const int lane = tid & 63;
    const int wave = tid >> 6;

    // ===================== stage P: all conversions + biases =====================
    {
        // one 8-element cvt chunk per thread: 256*512 = 131072 chunks total
        const int t = bid * 512 + tid;
        if (t < 32768)       cvt2048(W_xh0,        Wp,           t);
        else if (t < 98304)  cvt2048(W_xh_h,       w_xhh,        t - 32768);
        else                 cvt2048(W_hy_h + WSZ, Wp + 3 * WSZ, t - 98304);

        if (bid < 128) {
            // 128 transpose tiles: W_hy0^T -> wt, W_hy_h[0]^T -> wt+WSZ
            float (*ttr)[65] = (float(*)[65])smem;
            if (bid < 64) tcvt64_512(W_hy0,  wt,       bid,      tid, ttr);
            else          tcvt64_512(W_hy_h, wt + WSZ, bid - 64, tid, ttr);
        } else if (bid < 192) {
            // bias rows 1..2: bias[1+li][j] = b_hh + b_xh + W_xh_h[li][j,:] . b_hy_prev
            // 2 j per wave: 64 blocks * 8 waves * 2 = 1024 j
            const int gw = (bid - 128) * 8 + wave;
            const int jg = gw * 2;
            const int li = jg >> 9;
            const int jb = jg & 511;
            const float* __restrict__ W  = W_xh_h + (size_t)li * WSZ;
            const float* __restrict__ bh = li ? b_hy_h : b_hy0;
            const float4 h0 = *(const float4*)&bh[lane * 8];
            const float4 h1 = *(const float4*)&bh[lane * 8 + 4];
            #pragma unroll
            for (int u = 0; u < 2; ++u) {
                const int j = jb + u;
                const float4 w0 = *(const float4*)&W[(size_t)j * 512 + lane * 8];
                const float4 w1 = *(const float4*)&W[(size_t)j * 512 + lane * 8 + 4];
                float s = w0.x*h0.x + w0.y*h0.y + w0.z*h0.z + w0.w*h0.w
                        + w1.x*h1.x + w1.y*h1.y + w1.z*h1.z + w1.w*h1.w;
                #pragma unroll
                for (int off = 32; off; off >>= 1) s += __shfl_xor(s, off, 64);
                if (lane == 0)
                    bias[(1 + li) * KDIM + j] =
                        b_hh_h[li * KDIM + j] + b_xh_h[li * KDIM + j] + s;
            }
        } else if (bid == 192) {
            // bias rows 0 and 3 (trivial)
            bias[tid] = b_xh0[tid] + b_hh0[tid];
            bias[3 * KDIM + tid] = b_hy_h[KDIM + tid];
        }
    }

    cg::this_grid().sync();

    // ===================== stage F: W_eff folds (32 blocks, 512 threads) =====================
    // W_eff[li] = W_hh_h[li] + W_xh_h[li] @ W_hy_prev  -> Wp[1+li]
    if (bid < 32) {
        f16 (*A_s)[64] = (f16(*)[64])smem;
        f16 (*B_s)[64] = (f16(*)[64])(smem + 16384);

        const int fold = bid >> 4;
        const int fb   = bid & 15;
        const size_t off = (size_t)fold * WSZ;
        const f16*   __restrict__ A    = w_xhh + off;
        const f16*   __restrict__ W    = wt + off;
        const float* __restrict__ Cadd = W_hh_h + off;
        f16*         __restrict__ Cp   = Wp + WSZ + off;

        const int n0 = (fb >> 2) * 128;
        const int j0 = (fb & 3) * 128;
        const int wm = wave >> 2, wn = wave & 3;       // 2 x 4 wave grid
        const int fr = lane & 15, q = lane >> 4, sw = fr & 7;
        const int ar8 = lane >> 3;
        const int ach = (lane & 7) ^ ar8;

        f32x4 acc[4][2] = {};

        for (int kt = 0; kt < 8; ++kt) {
            const int k0 = kt * 64;
            #pragma unroll
            for (int p = 0; p < 2; ++p) {
                const int r8 = wave * 16 + p * 8;
                GLOAD_LDS16(&A[(size_t)(n0 + r8 + ar8) * KDIM + k0 + (ach << 3)], &A_s[r8][0]);
                GLOAD_LDS16(&W[(size_t)(j0 + r8 + ar8) * KDIM + k0 + (ach << 3)], &B_s[r8][0]);
            }
            __syncthreads();
            #pragma unroll
            for (int kc = 0; kc < 8; kc += 4) {
                f16x8 a[4], b[2];
                #pragma unroll
                for (int t = 0; t < 4; ++t)
                    a[t] = *(const f16x8*)&A_s[wm * 64 + t * 16 + fr][((kc + q) ^ sw) << 3];
                #pragma unroll
                for (int t = 0; t < 2; ++t)
                    b[t] = *(const f16x8*)&B_s[wn * 32 + t * 16 + fr][((kc + q) ^ sw) << 3];
                #pragma unroll
                for (int im = 0; im < 4; ++im)
                    #pragma unroll
                    for (int jn = 0; jn < 2; ++jn)
                        acc[im][jn] = __builtin_amdgcn_mfma_f32_16x16x32_f16(
                            a[im], b[jn], acc[im][jn], 0, 0, 0);
            }
            __syncthreads();
        }

        const int r0 = q * 4;
        #pragma unroll
        for (int jn = 0; jn < 2; ++jn) {
            const int j = j0 + wn * 32 + jn * 16 + fr;
            #pragma unroll
            for (int im = 0; im < 4; ++im)
                #pragma unroll
                for (int r = 0; r < 4; ++r) {
                    const int n = n0 + wm * 64 + im * 16 + r0 + r;
                    Cp[(size_t)n * KDIM + j] =
                        (f16)(acc[im][jn][r] + Cadd[(size_t)n * KDIM + j]);
                }
        }
    }

    cg::this_grid().sync();

    // ===================== stage C: fused 4-phase chain (verbatim) =====================
    {
        f16 (*hbuf)[512] = (f16(*)[512])smem;

        const int n0  = bid * 128;
        const int fr  = lane & 15;
        const int q   = lane >> 4;
        const int j0w = wave * 64;

        // ---- stage X tile: fp32 -> f16 into hbuf (swizzled) ----
        {
            const int tk = tid >> 2;
            const int cq = tid & 3;
            const float* __restrict__ src = &xs[(size_t)(n0 + tk) * KDIM];
            #pragma unroll
            for (int kt = 0; kt < 16; ++kt) {
                const int k = kt * 32 + cq * 8;
                const float4 v0 = *(const float4*)&src[k];
                const float4 v1 = *(const float4*)&src[k + 4];
                f16x8 h;
                h[0]=(f16)v0.x; h[1]=(f16)v0.y; h[2]=(f16)v0.z; h[3]=(f16)v0.w;
                h[4]=(f16)v1.x; h[5]=(f16)v1.y; h[6]=(f16)v1.z; h[7]=(f16)v1.w;
                const int c = (k >> 3) ^ (tk & 7);
                *(f16x8*)&hbuf[tk][c << 3] = h;
            }
        }

        f32x4 acc[4][8];

        // ---- phases 0..2: h = tanh(h_prev @ W^T + b), in-place in LDS ----
        for (int ph = 0; ph < 3; ++ph) {
            const f16*   __restrict__ wp = Wp + (size_t)ph * WSZ;
            const float* __restrict__ bp = bias + ph * KDIM;
            f32x4 bv[4];
            #pragma unroll
            for (int jt = 0; jt < 4; ++jt)
                bv[jt] = *(const f32x4*)&bp[j0w + jt * 16 + q * 4];
            #pragma unroll
            for (int jt = 0; jt < 4; ++jt)
                #pragma unroll
                for (int mt = 0; mt < 8; ++mt)
                    acc[jt][mt] = bv[jt];

            __syncthreads();

            for (int kt = 0; kt < 16; ++kt) {
                f16x8 wf[4], hf[8];
                #pragma unroll
                for (int jt = 0; jt < 4; ++jt)
                    wf[jt] = *(const f16x8*)&wp[(size_t)(j0w + jt*16 + fr) * KDIM + kt*32 + q*8];
                #pragma unroll
                for (int mt = 0; mt < 8; ++mt) {
                    const int m = mt * 16 + fr;
                    const int c = (kt * 4 + q) ^ (m & 7);
                    hf[mt] = *(const f16x8*)&hbuf[m][c << 3];
                }
                #pragma unroll
                for (int jt = 0; jt < 4; ++jt)
                    #pragma unroll
                    for (int mt = 0; mt < 8; ++mt)
                        acc[jt][mt] = __builtin_amdgcn_mfma_f32_16x16x32_f16(
                            wf[jt], hf[mt], acc[jt][mt], 0, 0, 0);
            }

            __syncthreads();

            #pragma unroll
            for (int jt = 0; jt < 4; ++jt) {
                const int j0f  = j0w + jt * 16 + q * 4;
                const int c    = j0f >> 3;
                const int half = j0f & 7;
                #pragma unroll
                for (int mt = 0; mt < 8; ++mt) {
                    const int m = mt * 16 + fr;
                    f16x4 hv;
                    hv[0] = (f16)fast_tanh(acc[jt][mt][0]);
                    hv[1] = (f16)fast_tanh(acc[jt][mt][1]);
                    hv[2] = (f16)fast_tanh(acc[jt][mt][2]);
                    hv[3] = (f16)fast_tanh(acc[jt][mt][3]);
                    *(f16x4*)&hbuf[m][((c ^ (m & 7)) << 3) + half] = hv;
                }
            }
        }

        // ---- phase 3: y2 = h2 @ W_hy1^T + b -> global ----
        {
            const f16*   __restrict__ wp = Wp + (size_t)3 * WSZ;
            const float* __restrict__ bp = bias + 3 * KDIM;
            f32x4 bv[4];
            #pragma unroll
            for (int jt = 0; jt < 4; ++jt)
                bv[jt] = *(const f32x4*)&bp[j0w + jt * 16 + q * 4];
            #pragma unroll
            for (int jt = 0; jt < 4; ++jt)
                #pragma unroll
                for (int mt = 0; mt < 8; ++mt)
                    acc[jt][mt] = bv[jt];

            __syncthreads();

            if ((bid & 31) == 31) {
                const int f = tid;
                const int c = (f >> 3) ^ 7;
                out[(size_t)SLEN * BATCH * KDIM + (size_t)(bid >> 5) * KDIM + f] =
                    (float)hbuf[127][(c << 3) + (f & 7)];
            }

            for (int kt = 0; kt < 16; ++kt) {
                f16x8 wf[4], hf[8];
                #pragma unroll
                for (int jt = 0; jt < 4; ++jt)
                    wf[jt] = *(const f16x8*)&wp[(size_t)(j0w + jt*16 + fr) * KDIM + kt*32 + q*8];
                #pragma unroll
                for (int mt = 0; mt < 8; ++mt) {
                    const int m = mt * 16 + fr;
                    const int c = (kt * 4 + q) ^ (m & 7);
                    hf[mt] = *(const f16x8*)&hbuf[m][c << 3];
                }
                #pragma unroll
                for (int jt = 0; jt < 4; ++jt)
                    #pragma unroll
                    for (int mt = 0; mt < 8; ++mt)
                        acc[jt][mt] = __builtin_amdgcn_mfma_f32_16x16x32_f16(
                            wf[jt], hf[mt], acc[jt][mt], 0, 0, 0);
            }

            #pragma unroll
            for (int jt = 0; jt < 4; ++jt) {
                const int j = j0w + jt * 16 + q * 4;
                #pragma unroll
                for (int mt = 0; mt < 8; ++mt) {
                    const int n  = n0 + mt * 16 + fr;
                    const int s  = n & (SLEN - 1);
                    const int bb = n >> 12;
                    *(f32x4*)&out[(size_t)(s * BATCH + bb) * KDIM + j] = acc[jt][mt];
                }
            }
        }
    }
}

extern "C" void kernel_launch(void* const* d_in, const int* in_sizes, int n_in,
                              void* d_out, int out_size, void* d_ws, size_t ws_size,
                              hipStream_t stream)
{
    (void)in_sizes; (void)n_in; (void)out_size; (void)ws_size;

    const float* xs     = (const float*)d_in[0];
    const float* W_xh0  = (const float*)d_in[1];
    const float* b_xh0  = (const float*)d_in[2];
    /* d_in[3] = W_hh0 unused (hs==0; only its bias matters) */
    const float* b_hh0  = (const float*)d_in[4];
    const float* W_hy0  = (const float*)d_in[5];
    const float* b_hy0  = (const float*)d_in[6];
    const float* W_xh_h = (const float*)d_in[7];
    const float* b_xh_h = (const float*)d_in[8];
    const float* W_hh_h = (const float*)d_in[9];
    const float* b_hh_h = (const float*)d_in[10];
    const float* W_hy_h = (const float*)d_in[11];
    const float* b_hy_h = (const float*)d_in[12];
    float*       outp   = (float*)d_out;

    f16*   Wp    = (f16*)d_ws;                 // [4][WSZ] phase weights
    f16*   w_xhh = Wp + 4 * WSZ;               // fold inputs
    f16*   wt    = w_xhh + 2 * WSZ;            // W_hy0^T, W_hy_h[0]^T
    float* bias  = (float*)(wt + 2 * WSZ);     // [4][512]

    void* args[] = { (void*)&xs, (void*)&W_xh0, (void*)&b_xh0, (void*)&b_hh0,
                     (void*)&W_hy0, (void*)&b_hy0, (void*)&W_xh_h, (void*)&b_xh_h,
                     (void*)&W_hh_h, (void*)&b_hh_h, (void*)&W_hy_h, (void*)&b_hy_h,
                     (void*)&outp, (void*)&Wp, (void*)&w_xhh, (void*)&wt, (void*)&bias };

    hipLaunchCooperativeKernel((const void*)mega_kernel, dim3(256), dim3(512),
                               args, 0, stream);
}